// Round 1
// baseline (1709.184 us; speedup 1.0000x reference)
//
#include <hip/hip_runtime.h>
#include <math.h>

// Problem constants
#define Dm    1024
#define LOWm  512
#define Bm    8
#define SPASTm 8191
#define Sm    8192

// Output layout offsets (in floats): (out, ckv, kr, up) concatenated flat
constexpr size_t OUT_OFF_OUT = 0;
constexpr size_t OUT_OFF_CKV = (size_t)Bm * Dm;                         // 8192
constexpr size_t OUT_OFF_KR  = OUT_OFF_CKV + (size_t)Bm * Sm * LOWm;    // +33554432
constexpr size_t OUT_OFF_UP  = OUT_OFF_KR  + (size_t)Bm * Sm * Dm;      // +67108864

// Main fused kernel decomposition: 128 blocks per batch, 4 waves/block,
// 16 rows per wave -> 64 rows/block -> 8192 rows/batch.
#define NCHUNK 128
#define PARTSZ (Dm + 2)

// Workspace layout (floats). Total ~1.09M floats (~4.4 MB).
#define WS_Q    0                                   // [B][2D] scaled q
#define WS_CQ   (WS_Q   + Bm * 2 * Dm)              // [B][D]
#define WS_CKV  (WS_CQ  + Bm * Dm)                  // [B][LOW]
#define WS_PART (WS_CKV + Bm * LOWm)                // [B*NCHUNK][PARTSZ]
#define WS_ATTN (WS_PART + Bm * NCHUNK * PARTSZ)    // [B][D]

// ---------------------------------------------------------------------------
// k1a: per batch compute Cq = x@Wdq (-> ws), cur_ckv = x@Wdkv (-> ws and
// out ckv row 8191), cur_kr = x@Wkr (-> out kr row 8191).
// grid (8, 10), block 256: concatenated col space [Wdq 1024 | Wdkv 512 | Wkr 1024]
// ---------------------------------------------------------------------------
__global__ __launch_bounds__(256) void k1a(
    const float* __restrict__ x, const float* __restrict__ Wdq,
    const float* __restrict__ Wdkv, const float* __restrict__ Wkr,
    float* __restrict__ out, float* __restrict__ ws) {
  int b = blockIdx.x;
  int col = blockIdx.y * 256 + threadIdx.x;   // 0..2559
  __shared__ float xs[Dm];
  for (int i = threadIdx.x; i < Dm; i += 256) xs[i] = x[b * Dm + i];
  __syncthreads();
  float acc = 0.f;
  if (col < Dm) {                    // Wdq -> Cq
    int j = col;
    for (int i = 0; i < Dm; ++i) acc += xs[i] * Wdq[(size_t)i * Dm + j];
    ws[WS_CQ + b * Dm + j] = acc;
  } else if (col < Dm + LOWm) {      // Wdkv -> cur_ckv
    int j = col - Dm;
    for (int i = 0; i < Dm; ++i) acc += xs[i] * Wdkv[(size_t)i * LOWm + j];
    ws[WS_CKV + b * LOWm + j] = acc;
    out[OUT_OFF_CKV + ((size_t)b * Sm + SPASTm) * LOWm + j] = acc;
  } else {                           // Wkr -> cur_kr
    int j = col - Dm - LOWm;
    for (int i = 0; i < Dm; ++i) acc += xs[i] * Wkr[(size_t)i * Dm + j];
    out[OUT_OFF_KR + ((size_t)b * Sm + SPASTm) * Dm + j] = acc;
  }
}

// ---------------------------------------------------------------------------
// k1b: per batch compute Qc = Cq@Wuq, Qr = Cq@Wqr (-> ws q = [Qc,Qr]),
// cur_up = cur_ckv @ fused_upsample (-> out up row 8191).
// grid (8, 16), block 256: col space [Wuq 1024 | Wqr 1024 | fused 2048]
// ---------------------------------------------------------------------------
__global__ __launch_bounds__(256) void k1b(
    const float* __restrict__ Wuq, const float* __restrict__ Wqr,
    const float* __restrict__ Wup, float* __restrict__ out,
    float* __restrict__ ws) {
  int b = blockIdx.x;
  int col = blockIdx.y * 256 + threadIdx.x;   // 0..4095
  __shared__ float cqs[Dm];
  __shared__ float ckvs[LOWm];
  for (int i = threadIdx.x; i < Dm; i += 256) cqs[i] = ws[WS_CQ + b * Dm + i];
  for (int i = threadIdx.x; i < LOWm; i += 256) ckvs[i] = ws[WS_CKV + b * LOWm + i];
  __syncthreads();
  float acc = 0.f;
  if (col < Dm) {                    // Qc
    int j = col;
    for (int i = 0; i < Dm; ++i) acc += cqs[i] * Wuq[(size_t)i * Dm + j];
    ws[WS_Q + b * 2 * Dm + j] = acc;
  } else if (col < 2 * Dm) {         // Qr
    int j = col - Dm;
    for (int i = 0; i < Dm; ++i) acc += cqs[i] * Wqr[(size_t)i * Dm + j];
    ws[WS_Q + b * 2 * Dm + Dm + j] = acc;
  } else {                           // cur_up
    int j = col - 2 * Dm;
    for (int i = 0; i < LOWm; ++i) acc += ckvs[i] * Wup[(size_t)i * 2 * Dm + j];
    out[OUT_OFF_UP + ((size_t)b * Sm + SPASTm) * 2 * Dm + j] = acc;
  }
}

// ---------------------------------------------------------------------------
// k2: the fused cache-copy + online-softmax-attention partial kernel.
// grid = B*NCHUNK = 1024 blocks, 256 threads (4 waves). Wave w of block
// (b, chunk) handles rows [chunk*64 + w*16, +16). For each row:
//   - float4-load up row (2048 f), kr row (1024 f), ckv row (512 f)
//   - copy them to the output cache regions (rows < 8191; row 8191 was
//     written by k1 and is instead *read* from the output region)
//   - score = q . [up[0:1024], kr] (q pre-scaled, in LDS), wave-reduced
//   - online softmax: running m, l; per-lane 16-float v accumulator
// Waves combine in LDS; one partial (m, l, acc[1024]) per block -> ws.
// ---------------------------------------------------------------------------
__global__ __launch_bounds__(256) void k2(
    const float* __restrict__ ckv_c, const float* __restrict__ kr_c,
    const float* __restrict__ up_c, float* __restrict__ out,
    float* __restrict__ ws) {
  int b = blockIdx.x >> 7;          // / NCHUNK
  int chunk = blockIdx.x & (NCHUNK - 1);
  int w = threadIdx.x >> 6;
  int lane = threadIdx.x & 63;

  __shared__ __align__(16) float qs[2 * Dm];   // scaled q
  __shared__ float sacc[Dm];
  __shared__ float wm[4], wl[4];

  const float scale = 0.022097086912079608f;   // 1/sqrt(2*1024)
  for (int i = threadIdx.x; i < 2 * Dm; i += 256)
    qs[i] = ws[WS_Q + b * 2 * Dm + i] * scale;
  for (int i = threadIdx.x; i < Dm; i += 256) sacc[i] = 0.f;
  __syncthreads();

  const float4* q4 = reinterpret_cast<const float4*>(qs);

  float m = -INFINITY, l = 0.f;
  float acc[16];
#pragma unroll
  for (int t = 0; t < 16; ++t) acc[t] = 0.f;

  int row0 = chunk * 64 + w * 16;
  for (int it = 0; it < 16; ++it) {
    int r = row0 + it;
    bool past = (r < SPASTm);
    // Source rows: caches for past rows, output regions for the new row 8191
    const float* up_row  = past ? (up_c  + ((size_t)b * SPASTm + r) * 2048)
                                : (out + OUT_OFF_UP  + ((size_t)b * Sm + r) * 2048);
    const float* kr_row  = past ? (kr_c  + ((size_t)b * SPASTm + r) * 1024)
                                : (out + OUT_OFF_KR  + ((size_t)b * Sm + r) * 1024);
    const float* ckv_row = past ? (ckv_c + ((size_t)b * SPASTm + r) * 512)
                                : (out + OUT_OFF_CKV + ((size_t)b * Sm + r) * 512);
    const float4* up4  = reinterpret_cast<const float4*>(up_row);
    const float4* kr4p = reinterpret_cast<const float4*>(kr_row);
    const float4* cv4  = reinterpret_cast<const float4*>(ckv_row);

    float4 ku[4], vv[4], kr4[4], cv[2];
#pragma unroll
    for (int t = 0; t < 4; ++t) ku[t] = up4[t * 64 + lane];          // k_up half
#pragma unroll
    for (int t = 0; t < 4; ++t) vv[t] = up4[256 + t * 64 + lane];    // v half
#pragma unroll
    for (int t = 0; t < 4; ++t) kr4[t] = kr4p[t * 64 + lane];
#pragma unroll
    for (int t = 0; t < 2; ++t) cv[t] = cv4[t * 64 + lane];

    // dot(q, k) — lane partial over its 32 k_up + 32 kr elements
    float s = 0.f;
#pragma unroll
    for (int t = 0; t < 4; ++t) {
      float4 q = q4[t * 64 + lane];
      s += ku[t].x * q.x + ku[t].y * q.y + ku[t].z * q.z + ku[t].w * q.w;
    }
#pragma unroll
    for (int t = 0; t < 4; ++t) {
      float4 q = q4[256 + t * 64 + lane];
      s += kr4[t].x * q.x + kr4[t].y * q.y + kr4[t].z * q.z + kr4[t].w * q.w;
    }
    // wave-wide reduce (all lanes end with the full sum)
#pragma unroll
    for (int off = 32; off > 0; off >>= 1) s += __shfl_xor(s, off);

    // online softmax update
    float mn = fmaxf(m, s);
    float f = __expf(m - mn);
    float p = __expf(s - mn);
    l = l * f + p;
#pragma unroll
    for (int t = 0; t < 4; ++t) {
      acc[4 * t + 0] = acc[4 * t + 0] * f + p * vv[t].x;
      acc[4 * t + 1] = acc[4 * t + 1] * f + p * vv[t].y;
      acc[4 * t + 2] = acc[4 * t + 2] * f + p * vv[t].z;
      acc[4 * t + 3] = acc[4 * t + 3] * f + p * vv[t].w;
    }
    m = mn;

    if (past) {  // copy the row into the output cache regions
      float4* oup = reinterpret_cast<float4*>(out + OUT_OFF_UP + ((size_t)b * Sm + r) * 2048);
      float4* okr = reinterpret_cast<float4*>(out + OUT_OFF_KR + ((size_t)b * Sm + r) * 1024);
      float4* ocv = reinterpret_cast<float4*>(out + OUT_OFF_CKV + ((size_t)b * Sm + r) * 512);
#pragma unroll
      for (int t = 0; t < 4; ++t) oup[t * 64 + lane] = ku[t];
#pragma unroll
      for (int t = 0; t < 4; ++t) oup[256 + t * 64 + lane] = vv[t];
#pragma unroll
      for (int t = 0; t < 4; ++t) okr[t * 64 + lane] = kr4[t];
#pragma unroll
      for (int t = 0; t < 2; ++t) ocv[t * 64 + lane] = cv[t];
    }
  }

  // combine the 4 wave-partials of this block in LDS
  if (lane == 0) { wm[w] = m; wl[w] = l; }
  __syncthreads();
  float M = fmaxf(fmaxf(wm[0], wm[1]), fmaxf(wm[2], wm[3]));
  float f = __expf(m - M);   // m is wave-uniform
#pragma unroll
  for (int t = 0; t < 4; ++t) {
    atomicAdd(&sacc[t * 256 + 4 * lane + 0], acc[4 * t + 0] * f);
    atomicAdd(&sacc[t * 256 + 4 * lane + 1], acc[4 * t + 1] * f);
    atomicAdd(&sacc[t * 256 + 4 * lane + 2], acc[4 * t + 2] * f);
    atomicAdd(&sacc[t * 256 + 4 * lane + 3], acc[4 * t + 3] * f);
  }
  __syncthreads();
  size_t pb = WS_PART + (size_t)blockIdx.x * PARTSZ;
  if (threadIdx.x == 0) {
    float lt = wl[0] * __expf(wm[0] - M) + wl[1] * __expf(wm[1] - M) +
               wl[2] * __expf(wm[2] - M) + wl[3] * __expf(wm[3] - M);
    ws[pb] = M;
    ws[pb + 1] = lt;
  }
  for (int i = threadIdx.x; i < Dm; i += 256) ws[pb + 2 + i] = sacc[i];
}

// ---------------------------------------------------------------------------
// k3a: per batch combine NCHUNK partials -> attn[D] in ws. grid 8, block 256.
// ---------------------------------------------------------------------------
__global__ __launch_bounds__(256) void k3a(float* __restrict__ ws) {
  int b = blockIdx.x;
  int tid = threadIdx.x;
  __shared__ float red[256];
  __shared__ float fac[NCHUNK];
  const size_t pbase = WS_PART + (size_t)b * NCHUNK * PARTSZ;

  float m = -INFINITY;
  if (tid < NCHUNK) m = ws[pbase + (size_t)tid * PARTSZ];
  red[tid] = m;
  __syncthreads();
  for (int s = 128; s > 0; s >>= 1) {
    if (tid < s) red[tid] = fmaxf(red[tid], red[tid + s]);
    __syncthreads();
  }
  float M = red[0];
  __syncthreads();

  float lv = 0.f;
  if (tid < NCHUNK) {
    float f = __expf(m - M);
    fac[tid] = f;
    lv = ws[pbase + (size_t)tid * PARTSZ + 1] * f;
  }
  red[tid] = lv;
  __syncthreads();
  for (int s = 128; s > 0; s >>= 1) {
    if (tid < s) red[tid] += red[tid + s];
    __syncthreads();
  }
  float invL = 1.f / red[0];
  __syncthreads();

  for (int j = tid; j < Dm; j += 256) {
    float a = 0.f;
    for (int p = 0; p < NCHUNK; ++p)
      a += ws[pbase + (size_t)p * PARTSZ + 2 + j] * fac[p];
    ws[WS_ATTN + b * Dm + j] = a * invL;
  }
}

// ---------------------------------------------------------------------------
// k3b: out[b] = attn[b] @ Wo. grid (8, 4), block 256 (1 col/thread).
// ---------------------------------------------------------------------------
__global__ __launch_bounds__(256) void k3b(const float* __restrict__ Wo,
                                           float* __restrict__ out,
                                           const float* __restrict__ ws) {
  int b = blockIdx.x;
  int col = blockIdx.y * 256 + threadIdx.x;
  __shared__ float as[Dm];
  for (int i = threadIdx.x; i < Dm; i += 256) as[i] = ws[WS_ATTN + b * Dm + i];
  __syncthreads();
  float acc = 0.f;
  for (int i = 0; i < Dm; ++i) acc += as[i] * Wo[(size_t)i * Dm + col];
  out[OUT_OFF_OUT + b * Dm + col] = acc;
}

// ---------------------------------------------------------------------------
extern "C" void kernel_launch(void* const* d_in, const int* in_sizes, int n_in,
                              void* d_out, int out_size, void* d_ws, size_t ws_size,
                              hipStream_t stream) {
  const float* x     = (const float*)d_in[0];
  const float* ckv_c = (const float*)d_in[1];
  const float* kr_c  = (const float*)d_in[2];
  const float* up_c  = (const float*)d_in[3];
  const float* Wdq   = (const float*)d_in[4];
  const float* Wuq   = (const float*)d_in[5];
  const float* Wqr   = (const float*)d_in[6];
  const float* Wdkv  = (const float*)d_in[7];
  const float* Wkr   = (const float*)d_in[8];
  const float* Wup   = (const float*)d_in[9];
  const float* Wo    = (const float*)d_in[10];
  float* out = (float*)d_out;
  float* ws  = (float*)d_ws;

  k1a<<<dim3(Bm, 10), 256, 0, stream>>>(x, Wdq, Wdkv, Wkr, out, ws);
  k1b<<<dim3(Bm, 16), 256, 0, stream>>>(Wuq, Wqr, Wup, out, ws);
  k2<<<Bm * NCHUNK, 256, 0, stream>>>(ckv_c, kr_c, up_c, out, ws);
  k3a<<<Bm, 256, 0, stream>>>(ws);
  k3b<<<dim3(Bm, 4), 256, 0, stream>>>(Wo, out, ws);
}